// Round 6
// baseline (236.744 us; speedup 1.0000x reference)
//
#include <hip/hip_runtime.h>
#include <hip/hip_cooperative_groups.h>
#include <math.h>

namespace cg = cooperative_groups;

#define SEQ 512
#define HID 256
#define NH 8
#define DH 32
#define PI_F 3.14159265358979323846f
#define SCALE_F 0.17677669529663687f  /* 1/sqrt(32) */
#define LOG2E_F 1.4426950408889634f

// ws layout (float offsets)
#define OFF_OMEGA 0
#define OFF_AMP   131072
#define OFF_PHASE 262144
#define OFF_V     393216
#define OFF_CTX   524288
#define OFF_PQ    655360            /* 6 x 131072 (qkv split-K2 partials) */
#define OFF_PO    1441792           /* 4 x 131072 (out split-K4 partials) */

// one 64-wide K-chunk of a 64x64 tile: acc += A[r0..][k0..k0+64) * W[c0..][k0..]^T
// LDS: A natural [r][k] stride 68 (<=2-way), W transposed [k][c^swz], XOR-4
// swizzle keeps transpose-write and b128 compute-read <=2-way (free, m136).
__device__ __forceinline__ void gemm_chunk(
    const float* __restrict__ A, const float* __restrict__ W,
    int r0, int c0, int k0, int tid, float (&acc)[4][4],
    float* __restrict__ xs, float* __restrict__ wts)
{
#pragma unroll
    for (int it = 0; it < 4; it++) {
        int idx = tid + it * 256;
        int rr = idx >> 4, f4 = idx & 15;
        float4 av = *(const float4*)(A + (r0 + rr) * HID + k0 + 4 * f4);
        *(float4*)&xs[rr * 68 + 4 * f4] = av;
        float4 wv = *(const float4*)(W + (c0 + rr) * HID + k0 + 4 * f4);
        int cw = rr ^ ((f4 & 7) << 2);
        wts[(4 * f4 + 0) * 64 + cw] = wv.x;
        wts[(4 * f4 + 1) * 64 + cw] = wv.y;
        wts[(4 * f4 + 2) * 64 + cw] = wv.z;
        wts[(4 * f4 + 3) * 64 + cw] = wv.w;
    }
    __syncthreads();
    const int rg = tid >> 4, cgi = tid & 15;
#pragma unroll
    for (int g = 0; g < 16; g++) {
        float xfa[4][4], wfa[4][4];
#pragma unroll
        for (int i = 0; i < 4; i++) {
            float4 xv = *(const float4*)&xs[(4 * rg + i) * 68 + 4 * g];
            xfa[i][0] = xv.x; xfa[i][1] = xv.y; xfa[i][2] = xv.z; xfa[i][3] = xv.w;
        }
        const int sw = (g & 7) << 2;
#pragma unroll
        for (int m = 0; m < 4; m++) {
            float4 wv = *(const float4*)&wts[(4 * g + m) * 64 + ((4 * cgi) ^ sw)];
            wfa[m][0] = wv.x; wfa[m][1] = wv.y; wfa[m][2] = wv.z; wfa[m][3] = wv.w;
        }
#pragma unroll
        for (int m = 0; m < 4; m++)
#pragma unroll
            for (int i = 0; i < 4; i++)
#pragma unroll
                for (int j = 0; j < 4; j++)
                    acc[i][j] = fmaf(xfa[i][m], wfa[m][j], acc[i][j]);
    }
    __syncthreads();
}

// single cooperative kernel: 256 blocks x 256 threads, 5 phases, 4 grid syncs
__global__ __launch_bounds__(256, 1) void mega(
    const float* __restrict__ x,
    const float* __restrict__ wq, const float* __restrict__ bq,
    const float* __restrict__ wk, const float* __restrict__ bk,
    const float* __restrict__ wv, const float* __restrict__ bv,
    const float* __restrict__ wo, const float* __restrict__ bo,
    float* __restrict__ ws, float* __restrict__ out)
{
    cg::grid_group grid = cg::this_grid();
    const int tid = threadIdx.x;
    const int b = blockIdx.x;

    __shared__ float xs[64 * 68];
    __shared__ float wts[64 * 64];

    // ---- Phase 1: QKV GEMM, split-K2: 192 jobs (96 tiles x 2 k-halves) ----
    if (b < 192) {
        const int ks = b & 1;
        const int tile = b >> 1;           // 0..95
        const int which = tile >> 5;       // 0..2
        const int t = tile & 31;
        const int r0 = (t >> 2) * 64, c0 = (t & 3) * 64, k0 = ks * 128;
        const float* W = (which == 0) ? wq : (which == 1) ? wk : wv;
        float acc[4][4];
#pragma unroll
        for (int i = 0; i < 4; i++)
#pragma unroll
            for (int j = 0; j < 4; j++) acc[i][j] = 0.f;
        gemm_chunk(x, W, r0, c0, k0,      tid, acc, xs, wts);
        gemm_chunk(x, W, r0, c0, k0 + 64, tid, acc, xs, wts);
        float* P = ws + OFF_PQ + (which * 2 + ks) * (SEQ * HID);
        const int rg = tid >> 4, cgi = tid & 15;
#pragma unroll
        for (int i = 0; i < 4; i++) {
            float4 o4 = {acc[i][0], acc[i][1], acc[i][2], acc[i][3]};
            *(float4*)&P[(r0 + 4 * rg + i) * HID + c0 + 4 * cgi] = o4;
        }
    }
    grid.sync();

    // ---- Phase 2: reduce halves + bias + activations ----
    {
        const int gtid = b * 256 + tid;
#pragma unroll
        for (int s = 0; s < 6; s++) {
            int idx = gtid + s * 65536;       // 0..393215, each s-slice uniform in 'which'
            int which = idx >> 17;
            int o = idx & 131071;
            int c = idx & 255;
            const float* P = ws + OFF_PQ + which * 2 * (SEQ * HID) + o;
            float v = P[0] + P[SEQ * HID];
            if (which == 0) {
                v += bq[c];
                ws[OFF_OMEGA + o] = PI_F / (1.f + expf(-v));
            } else if (which == 1) {
                v += bk[c];
                ws[OFF_AMP + o] = 1.f / (1.f + expf(-v));
            } else {
                v += bv[c];
                ws[OFF_V + o] = v;
                ws[OFF_PHASE + o] = PI_F * tanhf(v);
            }
        }
    }
    grid.sync();

    // ---- Phase 3: wave attention, 2 units/block (unit = 8 i's x 1 head) ----
    {
        const int il = tid >> 5;
        const int d = tid & 31;
#pragma unroll
        for (int r = 0; r < 2; r++) {
            const int u = b * 2 + r;          // 0..511
            const int i8 = u >> 3;
            const int h = u & 7;
            const int i = i8 * 8 + il;
            const int col = h * DH + d;

            const float w  = ws[OFF_OMEGA + i * HID + col];
            const float aL = ws[OFF_AMP + i * HID + col] * (SCALE_F * LOG2E_F);
            const float ph = ws[OFF_PHASE + i * HID + col];
            const float* vcol = ws + OFF_V + col;

            float sw_, cw;
            sincosf(w, &sw_, &cw);
            float c2 = cw * cw - sw_ * sw_, s2 = 2.f * sw_ * cw;
            float c4 = c2 * c2 - s2 * s2,   s4 = 2.f * s2 * c2;

            float th0 = fmaf(w, (float)i, ph);
            float s0, cc0;
            sincosf(th0, &s0, &cc0);

            float pc[4], psn[4];
            pc[0] = cc0; psn[0] = s0;
#pragma unroll
            for (int k = 1; k < 4; k++) {
                float nc = pc[k - 1] * cw + psn[k - 1] * sw_;
                float ns = psn[k - 1] * cw - pc[k - 1] * sw_;
                pc[k] = nc; psn[k] = ns;
            }
            float p[4], q[4], den[4], num[4];
#pragma unroll
            for (int k = 0; k < 4; k++) {
                p[k] = aL * pc[k]; q[k] = aL * psn[k];
                den[k] = 0.f; num[k] = 0.f;
            }
#pragma unroll 4
            for (int t4 = 0; t4 < SEQ / 4; t4++) {
                float v0 = vcol[(4 * t4 + 0) * HID];
                float v1 = vcol[(4 * t4 + 1) * HID];
                float v2 = vcol[(4 * t4 + 2) * HID];
                float v3 = vcol[(4 * t4 + 3) * HID];
                float e0 = __builtin_amdgcn_exp2f(p[0]);
                float e1 = __builtin_amdgcn_exp2f(p[1]);
                float e2 = __builtin_amdgcn_exp2f(p[2]);
                float e3 = __builtin_amdgcn_exp2f(p[3]);
                den[0] += e0; den[1] += e1; den[2] += e2; den[3] += e3;
                num[0] = fmaf(e0, v0, num[0]);
                num[1] = fmaf(e1, v1, num[1]);
                num[2] = fmaf(e2, v2, num[2]);
                num[3] = fmaf(e3, v3, num[3]);
#pragma unroll
                for (int k = 0; k < 4; k++) {
                    float np = p[k] * c4 + q[k] * s4;
                    float nq = q[k] * c4 - p[k] * s4;
                    p[k] = np; q[k] = nq;
                }
            }
            float denom = (den[0] + den[1]) + (den[2] + den[3]);
            float numer = (num[0] + num[1]) + (num[2] + num[3]);
            ws[OFF_CTX + i * HID + col] = numer / denom;
        }
    }
    grid.sync();

    // ---- Phase 4: out GEMM, split-K4: 128 jobs (32 tiles x 4 k-slices) ----
    if (b < 128) {
        const int tile = b >> 2, ks = b & 3;
        const int r0 = (tile >> 2) * 64, c0 = (tile & 3) * 64, k0 = ks * 64;
        float acc[4][4];
#pragma unroll
        for (int i = 0; i < 4; i++)
#pragma unroll
            for (int j = 0; j < 4; j++) acc[i][j] = 0.f;
        gemm_chunk(ws + OFF_CTX, wo, r0, c0, k0, tid, acc, xs, wts);
        float* P = ws + OFF_PO + ks * (SEQ * HID);
        const int rg = tid >> 4, cgi = tid & 15;
#pragma unroll
        for (int i = 0; i < 4; i++) {
            float4 o4 = {acc[i][0], acc[i][1], acc[i][2], acc[i][3]};
            *(float4*)&P[(r0 + 4 * rg + i) * HID + c0 + 4 * cgi] = o4;
        }
    }
    grid.sync();

    // ---- Phase 5: reduce 4 slices + bias -> out ----
    {
        const int gtid = b * 256 + tid;
#pragma unroll
        for (int s = 0; s < 2; s++) {
            int idx = gtid + s * 65536;
            const float* P = ws + OFF_PO + idx;
            out[idx] = (P[0] + P[SEQ * HID]) + (P[2 * SEQ * HID] + P[3 * SEQ * HID])
                       + bo[idx & 255];
        }
    }
}

extern "C" void kernel_launch(void* const* d_in, const int* in_sizes, int n_in,
                              void* d_out, int out_size, void* d_ws, size_t ws_size,
                              hipStream_t stream) {
    const float* x  = (const float*)d_in[0];
    const float* wq = (const float*)d_in[1];
    const float* bq = (const float*)d_in[2];
    const float* wk = (const float*)d_in[3];
    const float* bk = (const float*)d_in[4];
    const float* wv = (const float*)d_in[5];
    const float* bv = (const float*)d_in[6];
    const float* wo = (const float*)d_in[7];
    const float* bo = (const float*)d_in[8];
    float* ws  = (float*)d_ws;
    float* out = (float*)d_out;

    void* args[] = {(void*)&x, (void*)&wq, (void*)&bq, (void*)&wk, (void*)&bk,
                    (void*)&wv, (void*)&bv, (void*)&wo, (void*)&bo,
                    (void*)&ws, (void*)&out};
    hipLaunchCooperativeKernel((const void*)mega, dim3(256), dim3(256),
                               args, 0, stream);
}

// Round 7
// 112.351 us; speedup vs baseline: 2.1072x; 2.1072x over previous
//
#include <hip/hip_runtime.h>
#include <math.h>

#define SEQ 512
#define HID 256
#define NH 8
#define DH 32
#define PI_F 3.14159265358979323846f
#define SCALE_F 0.17677669529663687f  /* 1/sqrt(32) */
#define LOG2E_F 1.4426950408889634f

// ws layout (float offsets)
#define OFF_OMEGA 0
#define OFF_AMP   131072
#define OFF_PHASE 262144
#define OFF_V     393216
#define OFF_CTX   524288

// ---------------- QKV projection, full-K, 64x32 tiles, fused act ----------
// grid 192 = which(3) x rt(8) x ct(8). Per thread: 4x2 micro-tile.
// A staged [r][68] (<=2-way banks), W staged k-major natural [c][68]
// (b128 reads over k; 4-way conflict on 2/38 instrs per g — 1.58x, cheap).
__global__ __launch_bounds__(256) void gemm_qkv_act(
    const float* __restrict__ x,
    const float* __restrict__ wq, const float* __restrict__ bq,
    const float* __restrict__ wk, const float* __restrict__ bk,
    const float* __restrict__ wv, const float* __restrict__ bv,
    float* __restrict__ ws)
{
    const int b = blockIdx.x;
    const int which = b >> 6;
    const int t = b & 63;
    const int r0 = (t >> 3) * 64;
    const int c0 = (t & 7) * 32;
    const float* W = (which == 0) ? wq : (which == 1) ? wk : wv;
    const float* B = (which == 0) ? bq : (which == 1) ? bk : bv;

    __shared__ float xs[64][68];
    __shared__ float wls[32][68];

    const int tid = threadIdx.x;
    const int rg = tid >> 4, cg = tid & 15;

    float acc[4][2];
#pragma unroll
    for (int i = 0; i < 4; i++) { acc[i][0] = 0.f; acc[i][1] = 0.f; }

    for (int k0 = 0; k0 < HID; k0 += 64) {
#pragma unroll
        for (int it = 0; it < 4; it++) {
            int idx = tid + it * 256;
            int rr = idx >> 4, f = idx & 15;
            *(float4*)&xs[rr][4 * f] =
                *(const float4*)(x + (r0 + rr) * HID + k0 + 4 * f);
        }
#pragma unroll
        for (int it = 0; it < 2; it++) {
            int idx = tid + it * 256;
            int cc = idx >> 4, f = idx & 15;
            *(float4*)&wls[cc][4 * f] =
                *(const float4*)(W + (c0 + cc) * HID + k0 + 4 * f);
        }
        __syncthreads();
#pragma unroll
        for (int g = 0; g < 16; g++) {
            float4 wv0 = *(const float4*)&wls[2 * cg + 0][4 * g];
            float4 wv1 = *(const float4*)&wls[2 * cg + 1][4 * g];
#pragma unroll
            for (int i = 0; i < 4; i++) {
                float4 xv = *(const float4*)&xs[4 * rg + i][4 * g];
                acc[i][0] = fmaf(xv.x, wv0.x, acc[i][0]);
                acc[i][0] = fmaf(xv.y, wv0.y, acc[i][0]);
                acc[i][0] = fmaf(xv.z, wv0.z, acc[i][0]);
                acc[i][0] = fmaf(xv.w, wv0.w, acc[i][0]);
                acc[i][1] = fmaf(xv.x, wv1.x, acc[i][1]);
                acc[i][1] = fmaf(xv.y, wv1.y, acc[i][1]);
                acc[i][1] = fmaf(xv.z, wv1.z, acc[i][1]);
                acc[i][1] = fmaf(xv.w, wv1.w, acc[i][1]);
            }
        }
        __syncthreads();
    }

    const float b0 = B[c0 + 2 * cg + 0];
    const float b1 = B[c0 + 2 * cg + 1];
#pragma unroll
    for (int i = 0; i < 4; i++) {
        int row = r0 + 4 * rg + i;
#pragma unroll
        for (int j = 0; j < 2; j++) {
            float val = acc[i][j] + (j ? b1 : b0);
            int o = row * HID + c0 + 2 * cg + j;
            if (which == 0) {
                ws[OFF_OMEGA + o] = PI_F / (1.f + expf(-val));
            } else if (which == 1) {
                ws[OFF_AMP + o] = 1.f / (1.f + expf(-val));
            } else {
                ws[OFF_V + o] = val;
                ws[OFF_PHASE + o] = PI_F * tanhf(val);
            }
        }
    }
}

// ---------------- output projection, full-K, 32x32 tiles, fused bias ------
// grid 128 = rt(16) x ct(8). Per thread: 2x2 micro-tile.
__global__ __launch_bounds__(256) void gemm_out_bias(
    const float* __restrict__ ctx, const float* __restrict__ wo,
    const float* __restrict__ bo, float* __restrict__ out)
{
    const int b = blockIdx.x;
    const int r0 = (b >> 3) * 32;
    const int c0 = (b & 7) * 32;

    __shared__ float xs[32][68];
    __shared__ float wls[32][68];

    const int tid = threadIdx.x;
    const int rg = tid >> 4, cg = tid & 15;

    float acc[2][2];
    acc[0][0] = acc[0][1] = acc[1][0] = acc[1][1] = 0.f;

    for (int k0 = 0; k0 < HID; k0 += 64) {
#pragma unroll
        for (int it = 0; it < 2; it++) {
            int idx = tid + it * 256;
            int rr = idx >> 4, f = idx & 15;
            *(float4*)&xs[rr][4 * f] =
                *(const float4*)(ctx + (r0 + rr) * HID + k0 + 4 * f);
            *(float4*)&wls[rr][4 * f] =
                *(const float4*)(wo + (c0 + rr) * HID + k0 + 4 * f);
        }
        __syncthreads();
#pragma unroll
        for (int g = 0; g < 16; g++) {
            float4 wv0 = *(const float4*)&wls[2 * cg + 0][4 * g];
            float4 wv1 = *(const float4*)&wls[2 * cg + 1][4 * g];
#pragma unroll
            for (int i = 0; i < 2; i++) {
                float4 xv = *(const float4*)&xs[2 * rg + i][4 * g];
                acc[i][0] = fmaf(xv.x, wv0.x, acc[i][0]);
                acc[i][0] = fmaf(xv.y, wv0.y, acc[i][0]);
                acc[i][0] = fmaf(xv.z, wv0.z, acc[i][0]);
                acc[i][0] = fmaf(xv.w, wv0.w, acc[i][0]);
                acc[i][1] = fmaf(xv.x, wv1.x, acc[i][1]);
                acc[i][1] = fmaf(xv.y, wv1.y, acc[i][1]);
                acc[i][1] = fmaf(xv.z, wv1.z, acc[i][1]);
                acc[i][1] = fmaf(xv.w, wv1.w, acc[i][1]);
            }
        }
        __syncthreads();
    }

    const float b0 = bo[c0 + 2 * cg + 0];
    const float b1 = bo[c0 + 2 * cg + 1];
#pragma unroll
    for (int i = 0; i < 2; i++) {
        int row = r0 + 2 * rg + i;
        out[row * HID + c0 + 2 * cg + 0] = acc[i][0] + b0;
        out[row * HID + c0 + 2 * cg + 1] = acc[i][1] + b1;
    }
}

// ---------------- wave-interference attention (unchanged from R4) ---------
__global__ __launch_bounds__(256) void wave_attn(const float* __restrict__ ws,
                                                 float* __restrict__ ctx)
{
    const int h  = blockIdx.y;
    const int il = threadIdx.x >> 5;
    const int d  = threadIdx.x & 31;
    const int i  = blockIdx.x * 8 + il;
    const int col = h * DH + d;

    const float w  = ws[OFF_OMEGA + i * HID + col];
    const float aL = ws[OFF_AMP + i * HID + col] * (SCALE_F * LOG2E_F);
    const float ph = ws[OFF_PHASE + i * HID + col];
    const float* vcol = ws + OFF_V + col;

    float sw_, cw;
    sincosf(w, &sw_, &cw);
    float c2 = cw * cw - sw_ * sw_, s2 = 2.f * sw_ * cw;
    float c4 = c2 * c2 - s2 * s2,   s4 = 2.f * s2 * c2;

    float th0 = fmaf(w, (float)i, ph);
    float s0, cc0;
    sincosf(th0, &s0, &cc0);

    float pc[4], psn[4];
    pc[0] = cc0; psn[0] = s0;
#pragma unroll
    for (int k = 1; k < 4; k++) {
        float nc = pc[k - 1] * cw + psn[k - 1] * sw_;
        float ns = psn[k - 1] * cw - pc[k - 1] * sw_;
        pc[k] = nc; psn[k] = ns;
    }
    float p[4], q[4], den[4], num[4];
#pragma unroll
    for (int k = 0; k < 4; k++) {
        p[k] = aL * pc[k]; q[k] = aL * psn[k];
        den[k] = 0.f; num[k] = 0.f;
    }

#pragma unroll 4
    for (int t = 0; t < SEQ / 4; t++) {
        float v0 = vcol[(4 * t + 0) * HID];
        float v1 = vcol[(4 * t + 1) * HID];
        float v2v = vcol[(4 * t + 2) * HID];
        float v3 = vcol[(4 * t + 3) * HID];
        float e0 = __builtin_amdgcn_exp2f(p[0]);
        float e1 = __builtin_amdgcn_exp2f(p[1]);
        float e2 = __builtin_amdgcn_exp2f(p[2]);
        float e3 = __builtin_amdgcn_exp2f(p[3]);
        den[0] += e0; den[1] += e1; den[2] += e2; den[3] += e3;
        num[0] = fmaf(e0, v0, num[0]);
        num[1] = fmaf(e1, v1, num[1]);
        num[2] = fmaf(e2, v2v, num[2]);
        num[3] = fmaf(e3, v3, num[3]);
#pragma unroll
        for (int k = 0; k < 4; k++) {
            float np = p[k] * c4 + q[k] * s4;
            float nq = q[k] * c4 - p[k] * s4;
            p[k] = np; q[k] = nq;
        }
    }
    float denom = (den[0] + den[1]) + (den[2] + den[3]);
    float numer = (num[0] + num[1]) + (num[2] + num[3]);
    ctx[i * HID + col] = numer / denom;
}

extern "C" void kernel_launch(void* const* d_in, const int* in_sizes, int n_in,
                              void* d_out, int out_size, void* d_ws, size_t ws_size,
                              hipStream_t stream) {
    const float* x  = (const float*)d_in[0];
    const float* wq = (const float*)d_in[1];
    const float* bq = (const float*)d_in[2];
    const float* wk = (const float*)d_in[3];
    const float* bk = (const float*)d_in[4];
    const float* wv = (const float*)d_in[5];
    const float* bv = (const float*)d_in[6];
    const float* wo = (const float*)d_in[7];
    const float* bo = (const float*)d_in[8];

    float* ws = (float*)d_ws;

    hipLaunchKernelGGL(gemm_qkv_act, dim3(192), dim3(256), 0, stream,
                       x, wq, bq, wk, bk, wv, bv, ws);
    hipLaunchKernelGGL(wave_attn, dim3(SEQ / 8, NH), dim3(256), 0, stream,
                       ws, ws + OFF_CTX);
    hipLaunchKernelGGL(gemm_out_bias, dim3(128), dim3(256), 0, stream,
                       ws + OFF_CTX, wo, bo, (float*)d_out);
}

// Round 8
// 109.361 us; speedup vs baseline: 2.1648x; 1.0273x over previous
//
#include <hip/hip_runtime.h>
#include <math.h>

#define SEQ 512
#define HID 256
#define NH 8
#define DH 32
#define PI_F 3.14159265358979323846f
#define SCALE_F 0.17677669529663687f  /* 1/sqrt(32) */
#define LOG2E_F 1.4426950408889634f

// ws layout (float offsets)
#define OFF_OMEGA 0
#define OFF_AMP   131072
#define OFF_PHASE 262144
#define OFF_V     393216

// ---------------- K1: QKV projection + activations + bias-init of out -----
// grid 192 = which(3) x rt(8) x ct(8), 64x32 tiles, full K, reg-prefetch
// pipelined staging. Also seeds out[] with bo (so K2 can atomically add).
__global__ __launch_bounds__(256) void gemm_qkv_act(
    const float* __restrict__ x,
    const float* __restrict__ wq, const float* __restrict__ bq,
    const float* __restrict__ wk, const float* __restrict__ bk,
    const float* __restrict__ wv, const float* __restrict__ bv,
    const float* __restrict__ bo,
    float* __restrict__ ws, float* __restrict__ out)
{
    const int b = blockIdx.x;
    const int which = b >> 6;
    const int t = b & 63;
    const int r0 = (t >> 3) * 64;
    const int c0 = (t & 7) * 32;
    const float* W = (which == 0) ? wq : (which == 1) ? wk : wv;
    const float* B = (which == 0) ? bq : (which == 1) ? bk : bv;

    __shared__ float xs[64][68];
    __shared__ float wls[32][68];

    const int tid = threadIdx.x;
    const int rg = tid >> 4, cg = tid & 15;

    // bias-init slice of out: 131072 elems / 192 blocks
    {
        int base = b * 256 + tid;           // 0..49151
        for (int idx = base; idx < SEQ * HID; idx += 192 * 256)
            out[idx] = bo[idx & 255];
    }

    // prefetch chunk 0
    const int arr = tid >> 4, af = tid & 15;       // xs: 4 iters pattern
    float4 pa[4], pw[2];
#pragma unroll
    for (int it = 0; it < 4; it++)
        pa[it] = *(const float4*)(x + (r0 + arr + it * 16) * HID + 4 * af);
#pragma unroll
    for (int it = 0; it < 2; it++)
        pw[it] = *(const float4*)(W + (c0 + arr + it * 16) * HID + 4 * af);

    float acc[4][2];
#pragma unroll
    for (int i = 0; i < 4; i++) { acc[i][0] = 0.f; acc[i][1] = 0.f; }

    for (int k0 = 0; k0 < HID; k0 += 64) {
#pragma unroll
        for (int it = 0; it < 4; it++)
            *(float4*)&xs[arr + it * 16][4 * af] = pa[it];
#pragma unroll
        for (int it = 0; it < 2; it++)
            *(float4*)&wls[arr + it * 16][4 * af] = pw[it];
        __syncthreads();

        if (k0 + 64 < HID) {    // issue next chunk's loads; overlap compute
#pragma unroll
            for (int it = 0; it < 4; it++)
                pa[it] = *(const float4*)(x + (r0 + arr + it * 16) * HID + k0 + 64 + 4 * af);
#pragma unroll
            for (int it = 0; it < 2; it++)
                pw[it] = *(const float4*)(W + (c0 + arr + it * 16) * HID + k0 + 64 + 4 * af);
        }

#pragma unroll
        for (int g = 0; g < 16; g++) {
            float4 wv0 = *(const float4*)&wls[2 * cg + 0][4 * g];
            float4 wv1 = *(const float4*)&wls[2 * cg + 1][4 * g];
#pragma unroll
            for (int i = 0; i < 4; i++) {
                float4 xv = *(const float4*)&xs[4 * rg + i][4 * g];
                acc[i][0] = fmaf(xv.x, wv0.x, acc[i][0]);
                acc[i][0] = fmaf(xv.y, wv0.y, acc[i][0]);
                acc[i][0] = fmaf(xv.z, wv0.z, acc[i][0]);
                acc[i][0] = fmaf(xv.w, wv0.w, acc[i][0]);
                acc[i][1] = fmaf(xv.x, wv1.x, acc[i][1]);
                acc[i][1] = fmaf(xv.y, wv1.y, acc[i][1]);
                acc[i][1] = fmaf(xv.z, wv1.z, acc[i][1]);
                acc[i][1] = fmaf(xv.w, wv1.w, acc[i][1]);
            }
        }
        __syncthreads();
    }

    const float b0 = B[c0 + 2 * cg + 0];
    const float b1 = B[c0 + 2 * cg + 1];
#pragma unroll
    for (int i = 0; i < 4; i++) {
        int row = r0 + 4 * rg + i;
#pragma unroll
        for (int j = 0; j < 2; j++) {
            float val = acc[i][j] + (j ? b1 : b0);
            int o = row * HID + c0 + 2 * cg + j;
            if (which == 0) {
                ws[OFF_OMEGA + o] = PI_F / (1.f + expf(-val));
            } else if (which == 1) {
                ws[OFF_AMP + o] = 1.f / (1.f + expf(-val));
            } else {
                ws[OFF_V + o] = val;
                ws[OFF_PHASE + o] = PI_F * tanhf(val);
            }
        }
    }
}

// ---------------- K2: wave attention + fused out-projection partial -------
// grid 512: b -> (i8 = b>>3, h = b&7). thread = (il = tid>>5, d = tid&31).
// Attention exactly as the proven R4 kernel; then ctx slice [8 rows][32 k]
// goes to LDS, wo k-slice [256 c][32 k] staged (32 KB), each thread computes
// 8 out-partials and atomicAdds into bias-seeded out.
__global__ __launch_bounds__(256) void wave_attn_out(
    const float* __restrict__ ws, const float* __restrict__ wo,
    float* __restrict__ out)
{
    const int b  = blockIdx.x;
    const int i8 = b >> 3;
    const int h  = b & 7;
    const int il = threadIdx.x >> 5;
    const int d  = threadIdx.x & 31;
    const int i  = i8 * 8 + il;
    const int col = h * DH + d;
    const int tid = threadIdx.x;

    __shared__ float wo_l[256][33];
    __shared__ float ctx_l[8][33];

    // stage wo[:, h*32 .. h*32+32) -> wo_l[c][kk], coalesced
#pragma unroll
    for (int it = 0; it < 8; it++) {
        int idx = tid + it * 256;         // 0..2047
        int c = idx >> 3, f = idx & 7;
        float4 wv = *(const float4*)(wo + c * HID + h * DH + 4 * f);
        wo_l[c][4 * f + 0] = wv.x;
        wo_l[c][4 * f + 1] = wv.y;
        wo_l[c][4 * f + 2] = wv.z;
        wo_l[c][4 * f + 3] = wv.w;
    }

    const float w  = ws[OFF_OMEGA + i * HID + col];
    const float aL = ws[OFF_AMP + i * HID + col] * (SCALE_F * LOG2E_F);
    const float ph = ws[OFF_PHASE + i * HID + col];
    const float* vcol = ws + OFF_V + col;

    float sw_, cw;
    sincosf(w, &sw_, &cw);
    float c2 = cw * cw - sw_ * sw_, s2 = 2.f * sw_ * cw;
    float c4 = c2 * c2 - s2 * s2,   s4 = 2.f * s2 * c2;

    float th0 = fmaf(w, (float)i, ph);
    float s0, cc0;
    sincosf(th0, &s0, &cc0);

    float pc[4], psn[4];
    pc[0] = cc0; psn[0] = s0;
#pragma unroll
    for (int k = 1; k < 4; k++) {
        float nc = pc[k - 1] * cw + psn[k - 1] * sw_;
        float ns = psn[k - 1] * cw - pc[k - 1] * sw_;
        pc[k] = nc; psn[k] = ns;
    }
    float p[4], q[4], den[4], num[4];
#pragma unroll
    for (int k = 0; k < 4; k++) {
        p[k] = aL * pc[k]; q[k] = aL * psn[k];
        den[k] = 0.f; num[k] = 0.f;
    }

#pragma unroll 4
    for (int t = 0; t < SEQ / 4; t++) {
        float v0 = vcol[(4 * t + 0) * HID];
        float v1 = vcol[(4 * t + 1) * HID];
        float v2v = vcol[(4 * t + 2) * HID];
        float v3 = vcol[(4 * t + 3) * HID];
        float e0 = __builtin_amdgcn_exp2f(p[0]);
        float e1 = __builtin_amdgcn_exp2f(p[1]);
        float e2 = __builtin_amdgcn_exp2f(p[2]);
        float e3 = __builtin_amdgcn_exp2f(p[3]);
        den[0] += e0; den[1] += e1; den[2] += e2; den[3] += e3;
        num[0] = fmaf(e0, v0, num[0]);
        num[1] = fmaf(e1, v1, num[1]);
        num[2] = fmaf(e2, v2v, num[2]);
        num[3] = fmaf(e3, v3, num[3]);
#pragma unroll
        for (int k = 0; k < 4; k++) {
            float np = p[k] * c4 + q[k] * s4;
            float nq = q[k] * c4 - p[k] * s4;
            p[k] = np; q[k] = nq;
        }
    }
    float denom = (den[0] + den[1]) + (den[2] + den[3]);
    float numer = (num[0] + num[1]) + (num[2] + num[3]);

    __syncthreads();                      // wo_l staged; ctx_l safe to write
    ctx_l[il][d] = numer / denom;
    __syncthreads();

    // out partial: rows i8*8..+8, cols c = d + 32m, k-slice = head h
    float ctx_r[32];
#pragma unroll
    for (int kk = 0; kk < 32; kk++) ctx_r[kk] = ctx_l[il][kk];
#pragma unroll
    for (int m = 0; m < 8; m++) {
        const int c = d + 32 * m;
        float s = 0.f;
#pragma unroll
        for (int kk = 0; kk < 32; kk++)
            s = fmaf(ctx_r[kk], wo_l[c][kk], s);
        atomicAdd(&out[i * HID + c], s);
    }
}

extern "C" void kernel_launch(void* const* d_in, const int* in_sizes, int n_in,
                              void* d_out, int out_size, void* d_ws, size_t ws_size,
                              hipStream_t stream) {
    const float* x  = (const float*)d_in[0];
    const float* wq = (const float*)d_in[1];
    const float* bq = (const float*)d_in[2];
    const float* wk = (const float*)d_in[3];
    const float* bk = (const float*)d_in[4];
    const float* wv = (const float*)d_in[5];
    const float* bv = (const float*)d_in[6];
    const float* wo = (const float*)d_in[7];
    const float* bo = (const float*)d_in[8];

    float* ws  = (float*)d_ws;
    float* out = (float*)d_out;

    hipLaunchKernelGGL(gemm_qkv_act, dim3(192), dim3(256), 0, stream,
                       x, wq, bq, wk, bk, wv, bv, bo, ws, out);
    hipLaunchKernelGGL(wave_attn_out, dim3(512), dim3(256), 0, stream,
                       ws, wo, out);
}